// Round 4
// baseline (1095.638 us; speedup 1.0000x reference)
//
#include <hip/hip_runtime.h>
#include <hip/hip_bf16.h>

constexpr int B_   = 2;
constexpr int N_   = 50000;
constexpr int E_   = 800000;
constexpr int CAP  = 64;    // per-node bucket capacity; P(deg>64)~1e-13 for Poisson(16)
constexpr int WPB  = 8;     // waves per block in fused kernel
constexpr float INV_SQRT_2 = 0.70710678118654752440f;

// ---------------------------------------------------------------------------
// Workspace layout (int32 elements):
//   counts     : [0, N)
//   sorted_pad : [N, N + 64*N)      (13 MB total)
// Chain is 2 dispatches: zero(counts) -> scatter_direct. No scan needed.
// ---------------------------------------------------------------------------

__global__ __launch_bounds__(256) void zero_kernel(int* __restrict__ p, int n) {
    int i = blockIdx.x * 256 + threadIdx.x;
    if (i < n) p[i] = 0;
}

__global__ __launch_bounds__(256) void scatter_direct_kernel(
    const int* __restrict__ src,
    const int* __restrict__ dst,
    int* counts,
    int* __restrict__ sorted_pad)
{
    int e = blockIdx.x * 256 + threadIdx.x;
    if (e < E_) {
        int d = dst[e];
        int pos = atomicAdd(&counts[d], 1);
        if (pos < CAP) sorted_pad[(d << 6) + pos] = src[e];
    }
}

// round-to-nearest-even f32 -> bf16 (values are finite normals here)
__device__ __forceinline__ unsigned f2bf(float f) {
    unsigned u = __float_as_uint(f);
    return (u + 0x7fffu + ((u >> 16) & 1u)) >> 16;
}

// ---------------------------------------------------------------------------
// Fused pull-aggregation + dual transform. ONE WAVE PER NODE d, BOTH batches:
//   - edge indices for d loaded once (wave-uniform -> s_load)
//   - gather: all 64 lanes (3 floats each, dwordx3), 4-edge unroll x 2 batches
//     -> 8 independent loads in flight per wave
//   - W staged as bf16-PACKED u32 pairs in LDS (16.6 KB for both matrices):
//     halves W LDS traffic, keeps total LDS ~41 KB -> 3 blocks/CU (24 waves).
// ---------------------------------------------------------------------------
__global__ __launch_bounds__(512) void fused_kernel(
    const float* __restrict__ x,
    const float* __restrict__ Wn,
    const float* __restrict__ We,
    const float* __restrict__ norm,
    const int* __restrict__ counts,
    const int* __restrict__ sorted_pad,
    float* __restrict__ out)
{
    __shared__ unsigned WnP[32][64];            // [i2][o] = bf16(W[o][2i2]) | bf16(W[o][2i2+1])<<16
    __shared__ unsigned WeP[32][64];
    __shared__ __align__(16) float xs[WPB][2][192];   // own-node x, per batch
    __shared__ __align__(16) float xa[WPB][2][192];   // aggregated neighbor x

    // Stage W packed-bf16 transposed: coalesced read, conflict-free write
    for (int t = threadIdx.x; t < 2048; t += 512) {
        int i2 = t >> 6, o = t & 63;
        float a = Wn[o * 64 + 2 * i2], b = Wn[o * 64 + 2 * i2 + 1];
        WnP[i2][o] = f2bf(a) | (f2bf(b) << 16);
        float c = We[o * 64 + 2 * i2], d2 = We[o * 64 + 2 * i2 + 1];
        WeP[i2][o] = f2bf(c) | (f2bf(d2) << 16);
    }

    const int wave = threadIdx.x >> 6;
    const int lane = threadIdx.x & 63;
    const int d = blockIdx.x * WPB + wave;      // 6250*8 = 50000 exact

    // stage own node's x for both batches (dwordx3 per lane, all lanes)
    {
        const float* p0 = x + (size_t)d * 192 + lane * 3;
        const float* p1 = p0 + (size_t)N_ * 192;
        float u0 = p0[0], u1 = p0[1], u2 = p0[2];
        float v0 = p1[0], v1 = p1[1], v2 = p1[2];
        xs[wave][0][lane * 3 + 0] = u0;
        xs[wave][0][lane * 3 + 1] = u1;
        xs[wave][0][lane * 3 + 2] = u2;
        xs[wave][1][lane * 3 + 0] = v0;
        xs[wave][1][lane * 3 + 1] = v1;
        xs[wave][1][lane * 3 + 2] = v2;
    }

    // pull-aggregate neighbors for BOTH batches; indices shared (uniform)
    const int degc = counts[d];
    const int deg = degc < CAP ? degc : CAP;
    const int* sp = sorted_pad + (d << 6);
    const float* xb0 = x + lane * 3;
    const float* xb1 = x + (size_t)N_ * 192 + lane * 3;

    float a00 = 0.f, a01 = 0.f, a02 = 0.f;
    float a10 = 0.f, a11 = 0.f, a12 = 0.f;
    int e = 0;
    for (; e + 3 < deg; e += 4) {
        int s0 = sp[e + 0], s1 = sp[e + 1], s2 = sp[e + 2], s3 = sp[e + 3];
        const float* q0 = xb0 + (size_t)s0 * 192;
        const float* q1 = xb0 + (size_t)s1 * 192;
        const float* q2 = xb0 + (size_t)s2 * 192;
        const float* q3 = xb0 + (size_t)s3 * 192;
        const float* r0 = xb1 + (size_t)s0 * 192;
        const float* r1 = xb1 + (size_t)s1 * 192;
        const float* r2 = xb1 + (size_t)s2 * 192;
        const float* r3 = xb1 + (size_t)s3 * 192;
        float t00 = q0[0], t01 = q0[1], t02 = q0[2];
        float t10 = q1[0], t11 = q1[1], t12 = q1[2];
        float t20 = q2[0], t21 = q2[1], t22 = q2[2];
        float t30 = q3[0], t31 = q3[1], t32 = q3[2];
        float u00 = r0[0], u01 = r0[1], u02 = r0[2];
        float u10 = r1[0], u11 = r1[1], u12 = r1[2];
        float u20 = r2[0], u21 = r2[1], u22 = r2[2];
        float u30 = r3[0], u31 = r3[1], u32 = r3[2];
        a00 += (t00 + t10) + (t20 + t30);
        a01 += (t01 + t11) + (t21 + t31);
        a02 += (t02 + t12) + (t22 + t32);
        a10 += (u00 + u10) + (u20 + u30);
        a11 += (u01 + u11) + (u21 + u31);
        a12 += (u02 + u12) + (u22 + u32);
    }
    for (; e < deg; ++e) {
        int s = sp[e];
        const float* q = xb0 + (size_t)s * 192;
        const float* r = xb1 + (size_t)s * 192;
        a00 += q[0]; a01 += q[1]; a02 += q[2];
        a10 += r[0]; a11 += r[1]; a12 += r[2];
    }
    xa[wave][0][lane * 3 + 0] = a00;
    xa[wave][0][lane * 3 + 1] = a01;
    xa[wave][0][lane * 3 + 2] = a02;
    xa[wave][1][lane * 3 + 0] = a10;
    xa[wave][1][lane * 3 + 1] = a11;
    xa[wave][1][lane * 3 + 2] = a12;

    __syncthreads();   // W tile visibility (xs/xa are wave-local)

    const float sc = norm[d];

    // matmul phase, one batch at a time (#pragma unroll 1 caps VGPR liveness)
    #pragma unroll 1
    for (int b = 0; b < 2; ++b) {
        const float4* xsv = (const float4*)&xs[wave][b][0];
        const float4* xav = (const float4*)&xa[wave][b][0];
        float an0 = 0.f, an1 = 0.f, an2 = 0.f;
        float ae0 = 0.f, ae1 = 0.f, ae2 = 0.f;
        #pragma unroll
        for (int i4 = 0; i4 < 16; ++i4) {
            unsigned un0 = WnP[2 * i4 + 0][lane];
            unsigned un1 = WnP[2 * i4 + 1][lane];
            unsigned ue0 = WeP[2 * i4 + 0][lane];
            unsigned ue1 = WeP[2 * i4 + 1][lane];
            float4 d0 = xsv[i4 * 3 + 0];   // x[i+0][k0..2], x[i+1][k0]
            float4 d1 = xsv[i4 * 3 + 1];   // x[i+1][k1..2], x[i+2][k0..1]
            float4 d2 = xsv[i4 * 3 + 2];   // x[i+2][k2],   x[i+3][k0..2]
            float4 g0 = xav[i4 * 3 + 0];
            float4 g1 = xav[i4 * 3 + 1];
            float4 g2 = xav[i4 * 3 + 2];
            float wn0 = __uint_as_float(un0 << 16);
            float wn1 = __uint_as_float(un0 & 0xffff0000u);
            float wn2 = __uint_as_float(un1 << 16);
            float wn3 = __uint_as_float(un1 & 0xffff0000u);
            float we0 = __uint_as_float(ue0 << 16);
            float we1 = __uint_as_float(ue0 & 0xffff0000u);
            float we2 = __uint_as_float(ue1 << 16);
            float we3 = __uint_as_float(ue1 & 0xffff0000u);

            an0 = fmaf(wn0, d0.x, an0); an1 = fmaf(wn0, d0.y, an1); an2 = fmaf(wn0, d0.z, an2);
            an0 = fmaf(wn1, d0.w, an0); an1 = fmaf(wn1, d1.x, an1); an2 = fmaf(wn1, d1.y, an2);
            an0 = fmaf(wn2, d1.z, an0); an1 = fmaf(wn2, d1.w, an1); an2 = fmaf(wn2, d2.x, an2);
            an0 = fmaf(wn3, d2.y, an0); an1 = fmaf(wn3, d2.z, an1); an2 = fmaf(wn3, d2.w, an2);

            ae0 = fmaf(we0, g0.x, ae0); ae1 = fmaf(we0, g0.y, ae1); ae2 = fmaf(we0, g0.z, ae2);
            ae0 = fmaf(we1, g0.w, ae0); ae1 = fmaf(we1, g1.x, ae1); ae2 = fmaf(we1, g1.y, ae2);
            ae0 = fmaf(we2, g1.z, ae0); ae1 = fmaf(we2, g1.w, ae1); ae2 = fmaf(we2, g2.x, ae2);
            ae0 = fmaf(we3, g2.y, ae0); ae1 = fmaf(we3, g2.z, ae1); ae2 = fmaf(we3, g2.w, ae2);
        }
        float* op = out + ((size_t)b * N_ + d) * 192 + lane * 3;
        op[0] = INV_SQRT_2 * fmaf(sc, ae0, an0);
        op[1] = INV_SQRT_2 * fmaf(sc, ae1, an1);
        op[2] = INV_SQRT_2 * fmaf(sc, ae2, an2);
    }
}

extern "C" void kernel_launch(void* const* d_in, const int* in_sizes, int n_in,
                              void* d_out, int out_size, void* d_ws, size_t ws_size,
                              hipStream_t stream) {
    const float* x    = (const float*)d_in[0];
    const float* Wn   = (const float*)d_in[1];
    const float* We   = (const float*)d_in[2];
    const float* norm = (const float*)d_in[3];
    const int*   src  = (const int*)d_in[4];
    const int*   dst  = (const int*)d_in[5];
    float* out = (float*)d_out;

    int* counts     = (int*)d_ws;
    int* sorted_pad = counts + N_;

    zero_kernel<<<(N_ + 255) / 256, 256, 0, stream>>>(counts, N_);
    scatter_direct_kernel<<<(E_ + 255) / 256, 256, 0, stream>>>(src, dst, counts, sorted_pad);
    fused_kernel<<<N_ / WPB, 512, 0, stream>>>(x, Wn, We, norm, counts, sorted_pad, out);
}

// Round 5
// 534.208 us; speedup vs baseline: 2.0510x; 2.0510x over previous
//
#include <hip/hip_runtime.h>
#include <hip/hip_bf16.h>

constexpr int B_   = 2;
constexpr int N_   = 50000;
constexpr int E_   = 800000;
constexpr int CAP  = 64;    // per-node bucket capacity; P(deg>64)~1e-13 for Poisson(16)
constexpr int WPB  = 8;     // waves per block in fused kernel
constexpr float INV_SQRT_2 = 0.70710678118654752440f;

// ---------------------------------------------------------------------------
// Workspace (int32 elements): counts [0,N), sorted_pad [N, N+64N)  (~13 MB)
// Chain: zero(counts) -> scatter_direct (bucket CSR, no scan).
// ---------------------------------------------------------------------------

__global__ __launch_bounds__(256) void zero_kernel(int* __restrict__ p, int n) {
    int i = blockIdx.x * 256 + threadIdx.x;
    if (i < n) p[i] = 0;
}

__global__ __launch_bounds__(256) void scatter_direct_kernel(
    const int* __restrict__ src,
    const int* __restrict__ dst,
    int* counts,
    int* __restrict__ sorted_pad)
{
    int t = blockIdx.x * 256 + threadIdx.x;          // E_/4 = 200000 quads
    if (t * 4 >= E_) return;
    int4 dv = ((const int4*)dst)[t];
    int4 sv = ((const int4*)src)[t];
    // 4 independent atomics -> overlap in flight
    int p0 = atomicAdd(&counts[dv.x], 1);
    int p1 = atomicAdd(&counts[dv.y], 1);
    int p2 = atomicAdd(&counts[dv.z], 1);
    int p3 = atomicAdd(&counts[dv.w], 1);
    if (p0 < CAP) sorted_pad[(dv.x << 6) + p0] = sv.x;
    if (p1 < CAP) sorted_pad[(dv.y << 6) + p1] = sv.y;
    if (p2 < CAP) sorted_pad[(dv.z << 6) + p2] = sv.z;
    if (p3 < CAP) sorted_pad[(dv.w << 6) + p3] = sv.w;
}

// round-to-nearest-even f32 -> bf16
__device__ __forceinline__ unsigned f2bf(float f) {
    unsigned u = __float_as_uint(f);
    return (u + 0x7fffu + ((u >> 16) & 1u)) >> 16;
}

// ---------------------------------------------------------------------------
// Fused pull-aggregation + dual transform. One wave per (b,d) pair (round-3
// structure: VGPR 40, no spill). Lanes 0..47 each own one float4 chunk of the
// 192-float node record; 4-edge unroll -> 4 float4 loads in flight.
// W staged as packed-bf16 u32 pairs: LDS 28.7 KB/block -> 4 blocks/CU
// (32 waves, 100% theoretical occupancy) and half the W LDS reads.
// ---------------------------------------------------------------------------
__global__ __launch_bounds__(512, 8) void fused_kernel(
    const float* __restrict__ x,
    const float* __restrict__ Wn,
    const float* __restrict__ We,
    const float* __restrict__ norm,
    const int* __restrict__ counts,
    const int* __restrict__ sorted_pad,
    float* __restrict__ out)
{
    __shared__ unsigned WnP[32][64];   // [i2][o] = bf16(W[o][2i2]) | bf16(W[o][2i2+1])<<16
    __shared__ unsigned WeP[32][64];
    __shared__ __align__(16) float xs[WPB][192];
    __shared__ __align__(16) float xa[WPB][192];

    for (int t = threadIdx.x; t < 2048; t += 512) {
        int i2 = t >> 6, o = t & 63;
        WnP[i2][o] = f2bf(Wn[o * 64 + 2 * i2]) | (f2bf(Wn[o * 64 + 2 * i2 + 1]) << 16);
        WeP[i2][o] = f2bf(We[o * 64 + 2 * i2]) | (f2bf(We[o * 64 + 2 * i2 + 1]) << 16);
    }
    __syncthreads();

    const int wave = threadIdx.x >> 6;
    const int lane = threadIdx.x & 63;
    const int p = blockIdx.x * WPB + wave;   // 12500*8 = 100000 exact
    const int b = p / N_;
    const int d = p - b * N_;

    // stage own node's x (float4, lanes 0..47)
    const float* xp = x + (size_t)p * 192;
    if (lane < 48) {
        ((float4*)&xs[wave][0])[lane] = ((const float4*)xp)[lane];
    }

    // pull-aggregate neighbor x: lane owns float4 chunk `lane` (0..47)
    const int degc = counts[d];
    const int deg = degc < CAP ? degc : CAP;
    const int* sp = sorted_pad + (d << 6);
    const float4* xb4 = (const float4*)(x + (size_t)b * N_ * 192);
    if (lane < 48) {
        float ax = 0.f, ay = 0.f, az = 0.f, aw = 0.f;
        int e = 0;
        for (; e + 3 < deg; e += 4) {
            int s0 = sp[e + 0];
            int s1 = sp[e + 1];
            int s2 = sp[e + 2];
            int s3 = sp[e + 3];
            float4 v0 = xb4[(size_t)s0 * 48 + lane];
            float4 v1 = xb4[(size_t)s1 * 48 + lane];
            float4 v2 = xb4[(size_t)s2 * 48 + lane];
            float4 v3 = xb4[(size_t)s3 * 48 + lane];
            ax += (v0.x + v1.x) + (v2.x + v3.x);
            ay += (v0.y + v1.y) + (v2.y + v3.y);
            az += (v0.z + v1.z) + (v2.z + v3.z);
            aw += (v0.w + v1.w) + (v2.w + v3.w);
        }
        for (; e < deg; ++e) {
            int s = sp[e];
            float4 v = xb4[(size_t)s * 48 + lane];
            ax += v.x; ay += v.y; az += v.z; aw += v.w;
        }
        float4 a4; a4.x = ax; a4.y = ay; a4.z = az; a4.w = aw;
        ((float4*)&xa[wave][0])[lane] = a4;
    }
    // wave-local LDS write->read ordering via lgkmcnt

    float an0 = 0.f, an1 = 0.f, an2 = 0.f;
    float ae0 = 0.f, ae1 = 0.f, ae2 = 0.f;
    const float4* xsv = (const float4*)&xs[wave][0];
    const float4* xav = (const float4*)&xa[wave][0];

    #pragma unroll
    for (int i4 = 0; i4 < 16; ++i4) {
        unsigned un0 = WnP[2 * i4 + 0][lane];
        unsigned un1 = WnP[2 * i4 + 1][lane];
        unsigned ue0 = WeP[2 * i4 + 0][lane];
        unsigned ue1 = WeP[2 * i4 + 1][lane];
        float4 d0 = xsv[i4 * 3 + 0];   // x[i+0][k0..2], x[i+1][k0]
        float4 d1 = xsv[i4 * 3 + 1];   // x[i+1][k1..2], x[i+2][k0..1]
        float4 d2 = xsv[i4 * 3 + 2];   // x[i+2][k2],   x[i+3][k0..2]
        float4 g0 = xav[i4 * 3 + 0];
        float4 g1 = xav[i4 * 3 + 1];
        float4 g2 = xav[i4 * 3 + 2];
        float wn0 = __uint_as_float(un0 << 16);
        float wn1 = __uint_as_float(un0 & 0xffff0000u);
        float wn2 = __uint_as_float(un1 << 16);
        float wn3 = __uint_as_float(un1 & 0xffff0000u);
        float we0 = __uint_as_float(ue0 << 16);
        float we1 = __uint_as_float(ue0 & 0xffff0000u);
        float we2 = __uint_as_float(ue1 << 16);
        float we3 = __uint_as_float(ue1 & 0xffff0000u);

        an0 = fmaf(wn0, d0.x, an0); an1 = fmaf(wn0, d0.y, an1); an2 = fmaf(wn0, d0.z, an2);
        an0 = fmaf(wn1, d0.w, an0); an1 = fmaf(wn1, d1.x, an1); an2 = fmaf(wn1, d1.y, an2);
        an0 = fmaf(wn2, d1.z, an0); an1 = fmaf(wn2, d1.w, an1); an2 = fmaf(wn2, d2.x, an2);
        an0 = fmaf(wn3, d2.y, an0); an1 = fmaf(wn3, d2.z, an1); an2 = fmaf(wn3, d2.w, an2);

        ae0 = fmaf(we0, g0.x, ae0); ae1 = fmaf(we0, g0.y, ae1); ae2 = fmaf(we0, g0.z, ae2);
        ae0 = fmaf(we1, g0.w, ae0); ae1 = fmaf(we1, g1.x, ae1); ae2 = fmaf(we1, g1.y, ae2);
        ae0 = fmaf(we2, g1.z, ae0); ae1 = fmaf(we2, g1.w, ae1); ae2 = fmaf(we2, g2.x, ae2);
        ae0 = fmaf(we3, g2.y, ae0); ae1 = fmaf(we3, g2.z, ae1); ae2 = fmaf(we3, g2.w, ae2);
    }

    const float sc = norm[d];
    const size_t off = (size_t)p * 192 + (size_t)lane * 3;
    out[off + 0] = INV_SQRT_2 * fmaf(sc, ae0, an0);
    out[off + 1] = INV_SQRT_2 * fmaf(sc, ae1, an1);
    out[off + 2] = INV_SQRT_2 * fmaf(sc, ae2, an2);
}

extern "C" void kernel_launch(void* const* d_in, const int* in_sizes, int n_in,
                              void* d_out, int out_size, void* d_ws, size_t ws_size,
                              hipStream_t stream) {
    const float* x    = (const float*)d_in[0];
    const float* Wn   = (const float*)d_in[1];
    const float* We   = (const float*)d_in[2];
    const float* norm = (const float*)d_in[3];
    const int*   src  = (const int*)d_in[4];
    const int*   dst  = (const int*)d_in[5];
    float* out = (float*)d_out;

    int* counts     = (int*)d_ws;
    int* sorted_pad = counts + N_;

    zero_kernel<<<(N_ + 255) / 256, 256, 0, stream>>>(counts, N_);
    scatter_direct_kernel<<<(E_ / 4 + 255) / 256, 256, 0, stream>>>(src, dst, counts, sorted_pad);
    fused_kernel<<<(B_ * N_) / WPB, 512, 0, stream>>>(x, Wn, We, norm, counts,
                                                      sorted_pad, out);
}

// Round 6
// 481.488 us; speedup vs baseline: 2.2755x; 1.1095x over previous
//
#include <hip/hip_runtime.h>
#include <hip/hip_bf16.h>

constexpr int B_   = 2;
constexpr int N_   = 50000;
constexpr int E_   = 800000;
constexpr int CAP  = 64;    // per-node bucket capacity; max deg ~40 for Poisson(16)
constexpr int WPB  = 8;     // waves per block in fused kernel
constexpr float INV_SQRT_2 = 0.70710678118654752440f;

constexpr int SCAT_THREADS = E_ / 4;                      // 200000
constexpr int SCAT_BLKS    = (SCAT_THREADS + 255) / 256;  // 782
constexpr int CONV_ELEMS   = B_ * N_ * 192;               // 19,200,000 f32
constexpr int CONV_THREADS = CONV_ELEMS / 8;              // 2,400,000
constexpr int CONV_BLKS    = CONV_THREADS / 256;          // 9375 exact

// ---------------------------------------------------------------------------
// Workspace (int32 elements):
//   counts     : [0, N)
//   sorted_pad : [N, N+64N)                (12.8 MB)
//   xbf        : [N+64N, +9.6M words)      (38.4 MB packed bf16 x)
// ---------------------------------------------------------------------------

__global__ __launch_bounds__(256) void zero_kernel(int* __restrict__ p, int n) {
    int i = blockIdx.x * 256 + threadIdx.x;
    if (i < n) p[i] = 0;
}

// round-to-nearest-even f32 -> bf16
__device__ __forceinline__ unsigned f2bf(float f) {
    unsigned u = __float_as_uint(f);
    return (u + 0x7fffu + ((u >> 16) & 1u)) >> 16;
}
__device__ __forceinline__ float blo(unsigned u) { return __uint_as_float(u << 16); }
__device__ __forceinline__ float bhi(unsigned u) { return __uint_as_float(u & 0xffff0000u); }

// ---------------------------------------------------------------------------
// Prep: ONE dispatch doing both (block-range split):
//   blocks [0, SCAT_BLKS)             : bucket-CSR edge scatter (atomic slots)
//   blocks [SCAT_BLKS, +CONV_BLKS)    : x f32 -> packed-bf16 slab conversion
// The BW-bound conversion hides the scatter's atomic round-trip latency.
// ---------------------------------------------------------------------------
__global__ __launch_bounds__(256) void prep_kernel(
    const int* __restrict__ src,
    const int* __restrict__ dst,
    const float* __restrict__ x,
    int* counts,
    int* __restrict__ sorted_pad,
    unsigned* __restrict__ xbf)
{
    const int bid = blockIdx.x;
    if (bid < SCAT_BLKS) {
        int t = bid * 256 + threadIdx.x;
        if (t < SCAT_THREADS) {
            int4 dv = ((const int4*)dst)[t];
            int4 sv = ((const int4*)src)[t];
            int p0 = atomicAdd(&counts[dv.x], 1);
            int p1 = atomicAdd(&counts[dv.y], 1);
            int p2 = atomicAdd(&counts[dv.z], 1);
            int p3 = atomicAdd(&counts[dv.w], 1);
            if (p0 < CAP) sorted_pad[(dv.x << 6) + p0] = sv.x;
            if (p1 < CAP) sorted_pad[(dv.y << 6) + p1] = sv.y;
            if (p2 < CAP) sorted_pad[(dv.z << 6) + p2] = sv.z;
            if (p3 < CAP) sorted_pad[(dv.w << 6) + p3] = sv.w;
        }
    } else {
        int t = (bid - SCAT_BLKS) * 256 + threadIdx.x;   // < CONV_THREADS exact
        const float4* xp = (const float4*)x;
        float4 a = xp[(size_t)t * 2 + 0];
        float4 c = xp[(size_t)t * 2 + 1];
        uint4 o;
        o.x = f2bf(a.x) | (f2bf(a.y) << 16);
        o.y = f2bf(a.z) | (f2bf(a.w) << 16);
        o.z = f2bf(c.x) | (f2bf(c.y) << 16);
        o.w = f2bf(c.z) | (f2bf(c.w) << 16);
        ((uint4*)xbf)[t] = o;
    }
}

// ---------------------------------------------------------------------------
// Fused pull-aggregation + dual transform. One wave per (b,d) pair (round-5
// structure). ALL x reads come from the packed-bf16 slab: lanes 0..47 own
// 8 B (4 elems) of each 384 B record; 8-edge unroll -> 8 uint2 loads in
// flight. Unpack to f32, accumulate f32, LDS/matmul/out identical to the
// measured-good round-5 body.
// ---------------------------------------------------------------------------
__global__ __launch_bounds__(512, 8) void fused_kernel(
    const float* __restrict__ Wn,
    const float* __restrict__ We,
    const float* __restrict__ norm,
    const int* __restrict__ counts,
    const int* __restrict__ sorted_pad,
    const unsigned* __restrict__ xbf,
    float* __restrict__ out)
{
    __shared__ unsigned WnP[32][64];   // [i2][o] packed bf16 W pairs
    __shared__ unsigned WeP[32][64];
    __shared__ __align__(16) float xs[WPB][192];
    __shared__ __align__(16) float xa[WPB][192];

    for (int t = threadIdx.x; t < 2048; t += 512) {
        int i2 = t >> 6, o = t & 63;
        WnP[i2][o] = f2bf(Wn[o * 64 + 2 * i2]) | (f2bf(Wn[o * 64 + 2 * i2 + 1]) << 16);
        WeP[i2][o] = f2bf(We[o * 64 + 2 * i2]) | (f2bf(We[o * 64 + 2 * i2 + 1]) << 16);
    }
    __syncthreads();

    const int wave = threadIdx.x >> 6;
    const int lane = threadIdx.x & 63;
    const int p = blockIdx.x * WPB + wave;   // 12500*8 = 100000 exact
    const int b = p / N_;
    const int d = p - b * N_;

    const int degc = counts[d];
    const int deg = degc < CAP ? degc : CAP;
    const int* sp = sorted_pad + (d << 6);
    // batch-b bf16 slab, uint2 (8 B) granularity: record = 48 uint2
    const uint2* xb2 = (const uint2*)xbf + (size_t)b * N_ * 48;

    if (lane < 48) {
        // own node -> xs
        uint2 ov = xb2[(size_t)d * 48 + lane];
        float4 s4;
        s4.x = blo(ov.x); s4.y = bhi(ov.x);
        s4.z = blo(ov.y); s4.w = bhi(ov.y);
        ((float4*)&xs[wave][0])[lane] = s4;

        // gather neighbors -> xa
        float ax = 0.f, ay = 0.f, az = 0.f, aw = 0.f;
        int e = 0;
        for (; e + 7 < deg; e += 8) {
            int s0 = sp[e + 0], s1 = sp[e + 1], s2 = sp[e + 2], s3 = sp[e + 3];
            int s4i = sp[e + 4], s5 = sp[e + 5], s6 = sp[e + 6], s7 = sp[e + 7];
            uint2 v0 = xb2[(size_t)s0 * 48 + lane];
            uint2 v1 = xb2[(size_t)s1 * 48 + lane];
            uint2 v2 = xb2[(size_t)s2 * 48 + lane];
            uint2 v3 = xb2[(size_t)s3 * 48 + lane];
            uint2 v4 = xb2[(size_t)s4i * 48 + lane];
            uint2 v5 = xb2[(size_t)s5 * 48 + lane];
            uint2 v6 = xb2[(size_t)s6 * 48 + lane];
            uint2 v7 = xb2[(size_t)s7 * 48 + lane];
            ax += ((blo(v0.x) + blo(v1.x)) + (blo(v2.x) + blo(v3.x)))
                + ((blo(v4.x) + blo(v5.x)) + (blo(v6.x) + blo(v7.x)));
            ay += ((bhi(v0.x) + bhi(v1.x)) + (bhi(v2.x) + bhi(v3.x)))
                + ((bhi(v4.x) + bhi(v5.x)) + (bhi(v6.x) + bhi(v7.x)));
            az += ((blo(v0.y) + blo(v1.y)) + (blo(v2.y) + blo(v3.y)))
                + ((blo(v4.y) + blo(v5.y)) + (blo(v6.y) + blo(v7.y)));
            aw += ((bhi(v0.y) + bhi(v1.y)) + (bhi(v2.y) + bhi(v3.y)))
                + ((bhi(v4.y) + bhi(v5.y)) + (bhi(v6.y) + bhi(v7.y)));
        }
        for (; e < deg; ++e) {
            int s = sp[e];
            uint2 v = xb2[(size_t)s * 48 + lane];
            ax += blo(v.x); ay += bhi(v.x);
            az += blo(v.y); aw += bhi(v.y);
        }
        float4 a4; a4.x = ax; a4.y = ay; a4.z = az; a4.w = aw;
        ((float4*)&xa[wave][0])[lane] = a4;
    }
    // wave-local LDS write->read ordering via lgkmcnt

    float an0 = 0.f, an1 = 0.f, an2 = 0.f;
    float ae0 = 0.f, ae1 = 0.f, ae2 = 0.f;
    const float4* xsv = (const float4*)&xs[wave][0];
    const float4* xav = (const float4*)&xa[wave][0];

    #pragma unroll
    for (int i4 = 0; i4 < 16; ++i4) {
        unsigned un0 = WnP[2 * i4 + 0][lane];
        unsigned un1 = WnP[2 * i4 + 1][lane];
        unsigned ue0 = WeP[2 * i4 + 0][lane];
        unsigned ue1 = WeP[2 * i4 + 1][lane];
        float4 d0 = xsv[i4 * 3 + 0];
        float4 d1 = xsv[i4 * 3 + 1];
        float4 d2 = xsv[i4 * 3 + 2];
        float4 g0 = xav[i4 * 3 + 0];
        float4 g1 = xav[i4 * 3 + 1];
        float4 g2 = xav[i4 * 3 + 2];
        float wn0 = blo(un0), wn1 = bhi(un0), wn2 = blo(un1), wn3 = bhi(un1);
        float we0 = blo(ue0), we1 = bhi(ue0), we2 = blo(ue1), we3 = bhi(ue1);

        an0 = fmaf(wn0, d0.x, an0); an1 = fmaf(wn0, d0.y, an1); an2 = fmaf(wn0, d0.z, an2);
        an0 = fmaf(wn1, d0.w, an0); an1 = fmaf(wn1, d1.x, an1); an2 = fmaf(wn1, d1.y, an2);
        an0 = fmaf(wn2, d1.z, an0); an1 = fmaf(wn2, d1.w, an1); an2 = fmaf(wn2, d2.x, an2);
        an0 = fmaf(wn3, d2.y, an0); an1 = fmaf(wn3, d2.z, an1); an2 = fmaf(wn3, d2.w, an2);

        ae0 = fmaf(we0, g0.x, ae0); ae1 = fmaf(we0, g0.y, ae1); ae2 = fmaf(we0, g0.z, ae2);
        ae0 = fmaf(we1, g0.w, ae0); ae1 = fmaf(we1, g1.x, ae1); ae2 = fmaf(we1, g1.y, ae2);
        ae0 = fmaf(we2, g1.z, ae0); ae1 = fmaf(we2, g1.w, ae1); ae2 = fmaf(we2, g2.x, ae2);
        ae0 = fmaf(we3, g2.y, ae0); ae1 = fmaf(we3, g2.z, ae1); ae2 = fmaf(we3, g2.w, ae2);
    }

    const float sc = norm[d];
    const size_t off = (size_t)p * 192 + (size_t)lane * 3;
    out[off + 0] = INV_SQRT_2 * fmaf(sc, ae0, an0);
    out[off + 1] = INV_SQRT_2 * fmaf(sc, ae1, an1);
    out[off + 2] = INV_SQRT_2 * fmaf(sc, ae2, an2);
}

extern "C" void kernel_launch(void* const* d_in, const int* in_sizes, int n_in,
                              void* d_out, int out_size, void* d_ws, size_t ws_size,
                              hipStream_t stream) {
    const float* x    = (const float*)d_in[0];
    const float* Wn   = (const float*)d_in[1];
    const float* We   = (const float*)d_in[2];
    const float* norm = (const float*)d_in[3];
    const int*   src  = (const int*)d_in[4];
    const int*   dst  = (const int*)d_in[5];
    float* out = (float*)d_out;

    int* counts        = (int*)d_ws;
    int* sorted_pad    = counts + N_;
    unsigned* xbf      = (unsigned*)(sorted_pad + (size_t)CAP * N_);

    zero_kernel<<<(N_ + 255) / 256, 256, 0, stream>>>(counts, N_);
    prep_kernel<<<SCAT_BLKS + CONV_BLKS, 256, 0, stream>>>(src, dst, x, counts,
                                                           sorted_pad, xbf);
    fused_kernel<<<(B_ * N_) / WPB, 512, 0, stream>>>(Wn, We, norm, counts,
                                                      sorted_pad, xbf, out);
}

// Round 7
// 448.977 us; speedup vs baseline: 2.4403x; 1.0724x over previous
//
#include <hip/hip_runtime.h>
#include <hip/hip_bf16.h>

constexpr int B_   = 2;
constexpr int N_   = 50000;
constexpr int E_   = 800000;
constexpr int WPB  = 8;
constexpr float INV_SQRT_2 = 0.70710678118654752440f;

constexpr int NBIN = 256;                        // buckets by dst>>8 (0..195 used)
constexpr int EPB  = 4096;                       // edges per hist/scatter block
constexpr int HBLK = (E_ + EPB - 1) / EPB;       // 196
constexpr int MSZ  = NBIN * HBLK;                // 50176 (counts matrix)
constexpr int SBLK = (MSZ + 255) / 256;          // 196

constexpr int CONV_THREADS = B_ * N_ * 192 / 8;  // 2,400,000
constexpr int CONV_BLKS    = CONV_THREADS / 256; // 9375

// ---------------------------------------------------------------------------
// Workspace (int32 elements), all regions fully written before read:
//   cnt      [0, MSZ)            per-(bin,block) histogram, cnt[bin*HBLK+blk]
//   scanned  [MSZ, 2M)           exclusive scan of cnt
//   bsum/bsx [2M, 2M+2*SBLK)     scan temporaries
//   mid      [.., +E)            (dst<<16|src) grouped by bucket
//   sorted   [.., +E)            src grouped by exact dst (compact CSR)
//   offsets  [.., +N+1)          CSR offsets
//   xbf      [aligned, +9.6M)    packed-bf16 x slab (38.4 MB)
// ---------------------------------------------------------------------------
constexpr int OFF_CNT  = 0;
constexpr int OFF_SCAN = MSZ;
constexpr int OFF_BSUM = 2 * MSZ;
constexpr int OFF_BSX  = 2 * MSZ + SBLK;
constexpr int OFF_MID  = 2 * MSZ + 2 * SBLK;
constexpr int OFF_SORT = OFF_MID + E_;
constexpr int OFF_OFFS = OFF_SORT + E_;
constexpr int OFF_XBF  = ((OFF_OFFS + N_ + 1 + 3) / 4) * 4;   // 16 B aligned

__device__ __forceinline__ unsigned f2bf(float f) {
    unsigned u = __float_as_uint(f);
    return (u + 0x7fffu + ((u >> 16) & 1u)) >> 16;
}
__device__ __forceinline__ float blo(unsigned u) { return __uint_as_float(u << 16); }
__device__ __forceinline__ float bhi(unsigned u) { return __uint_as_float(u & 0xffff0000u); }

// K1: block-range split: [0,HBLK) per-block LDS bucket histogram (no global
// atomics); [HBLK, +CONV_BLKS) f32 -> packed-bf16 slab conversion.
__global__ __launch_bounds__(256) void hist_conv_kernel(
    const int* __restrict__ dst, const float* __restrict__ x,
    int* __restrict__ cnt, unsigned* __restrict__ xbf)
{
    __shared__ int h[NBIN];
    const int bid = blockIdx.x;
    const int t = threadIdx.x;
    if (bid < HBLK) {
        h[t] = 0;
        __syncthreads();
        const int e0 = bid * EPB;
        #pragma unroll
        for (int it = 0; it < EPB / 256; ++it) {
            int e = e0 + it * 256 + t;
            if (e < E_) atomicAdd(&h[dst[e] >> 8], 1);   // LDS atomic
        }
        __syncthreads();
        cnt[t * HBLK + bid] = h[t];
    } else {
        int i = (bid - HBLK) * 256 + t;                  // < CONV_THREADS
        const float4* xp = (const float4*)x;
        float4 a = xp[(size_t)i * 2 + 0];
        float4 c = xp[(size_t)i * 2 + 1];
        uint4 o;
        o.x = f2bf(a.x) | (f2bf(a.y) << 16);
        o.y = f2bf(a.z) | (f2bf(a.w) << 16);
        o.z = f2bf(c.x) | (f2bf(c.y) << 16);
        o.w = f2bf(c.z) | (f2bf(c.w) << 16);
        ((uint4*)xbf)[i] = o;
    }
}

// K2/K3/K4: 3-phase exclusive scan of cnt[MSZ] -> scanned[MSZ] (round-3 proven)
__global__ __launch_bounds__(256) void scan_partial_kernel(const int* __restrict__ cnt,
                                                           int* __restrict__ bsum) {
    __shared__ int w[4];
    int idx = blockIdx.x * 256 + threadIdx.x;
    int v = (idx < MSZ) ? cnt[idx] : 0;
    #pragma unroll
    for (int o = 32; o; o >>= 1) v += __shfl_down(v, o, 64);
    if ((threadIdx.x & 63) == 0) w[threadIdx.x >> 6] = v;
    __syncthreads();
    if (threadIdx.x == 0) bsum[blockIdx.x] = w[0] + w[1] + w[2] + w[3];
}

__global__ __launch_bounds__(256) void scan_bsum_kernel(const int* __restrict__ bsum,
                                                        int* __restrict__ bsx) {
    __shared__ int tmp[256];
    int t = threadIdx.x;
    int v = (t < SBLK) ? bsum[t] : 0;
    tmp[t] = v;
    __syncthreads();
    #pragma unroll
    for (int off = 1; off < 256; off <<= 1) {
        int u = (t >= off) ? tmp[t - off] : 0;
        __syncthreads();
        tmp[t] += u;
        __syncthreads();
    }
    if (t < SBLK) bsx[t] = tmp[t] - v;
}

__global__ __launch_bounds__(256) void scan_final_kernel(const int* __restrict__ cnt,
                                                         const int* __restrict__ bsx,
                                                         int* __restrict__ scanned) {
    __shared__ int tmp[256];
    int idx = blockIdx.x * 256 + threadIdx.x;
    int t = threadIdx.x;
    int v = (idx < MSZ) ? cnt[idx] : 0;
    tmp[t] = v;
    __syncthreads();
    #pragma unroll
    for (int off = 1; off < 256; off <<= 1) {
        int u = (t >= off) ? tmp[t - off] : 0;
        __syncthreads();
        tmp[t] += u;
        __syncthreads();
    }
    if (idx < MSZ) scanned[idx] = bsx[blockIdx.x] + tmp[t] - v;
}

// K5: scatter edges into mid grouped by bucket. Ranks via LDS atomics only;
// each (block,bucket) writes a contiguous run -> L2-merged streaming writes.
__global__ __launch_bounds__(256) void mid_scatter_kernel(
    const int* __restrict__ src, const int* __restrict__ dst,
    const int* __restrict__ scanned, unsigned* __restrict__ mid)
{
    __shared__ int lbase[NBIN];
    __shared__ int lrank[NBIN];
    const int t = threadIdx.x, blk = blockIdx.x;
    lbase[t] = scanned[t * HBLK + blk];
    lrank[t] = 0;
    __syncthreads();
    const int e0 = blk * EPB;
    #pragma unroll
    for (int it = 0; it < EPB / 256; ++it) {
        int e = e0 + it * 256 + t;
        if (e < E_) {
            int d = dst[e];
            int bin = d >> 8;
            int r = atomicAdd(&lrank[bin], 1);           // LDS atomic
            mid[lbase[bin] + r] = ((unsigned)d << 16) | (unsigned)src[e];
        }
    }
}

// K6: one block per bucket: counting-sort by dst&255 -> compact CSR
// (offsets + sorted src). All stores contiguous within the bucket's region.
__global__ __launch_bounds__(256) void bucket_sort_kernel(
    const unsigned* __restrict__ mid, const int* __restrict__ scanned,
    int* __restrict__ sortedsrc, int* __restrict__ offsets)
{
    __shared__ int h[NBIN], pfx[NBIN], rank[NBIN];
    const int t = threadIdx.x, b = blockIdx.x;           // bucket 0..195
    const int r0 = scanned[b * HBLK];
    const int r1 = scanned[(b + 1) * HBLK];              // b<=195<255: valid
    h[t] = 0;
    __syncthreads();
    for (int e = r0 + t; e < r1; e += 256)
        atomicAdd(&h[(mid[e] >> 16) & 255], 1);          // LDS atomic
    __syncthreads();
    int v = h[t];
    pfx[t] = v;
    __syncthreads();
    #pragma unroll
    for (int off = 1; off < 256; off <<= 1) {
        int u = (t >= off) ? pfx[t - off] : 0;
        __syncthreads();
        pfx[t] += u;
        __syncthreads();
    }
    pfx[t] -= v;                                         // exclusive
    rank[t] = 0;
    int d = (b << 8) + t;
    if (d < N_) offsets[d] = r0 + pfx[t];
    if (b == 0 && t == 0) offsets[N_] = E_;
    __syncthreads();
    for (int e = r0 + t; e < r1; e += 256) {
        unsigned pk = mid[e];
        int bin = (pk >> 16) & 255;
        int slot = r0 + pfx[bin] + atomicAdd(&rank[bin], 1);
        sortedsrc[slot] = (int)(pk & 0xFFFFu);
    }
}

// K7: fused pull-aggregation + dual transform (round-6 body, compact CSR,
// full-line out stores via wave-local LDS transpose).
__global__ __launch_bounds__(512, 8) void fused_kernel(
    const float* __restrict__ Wn, const float* __restrict__ We,
    const float* __restrict__ norm, const int* __restrict__ offsets,
    const int* __restrict__ sortedsrc, const unsigned* __restrict__ xbf,
    float* __restrict__ out)
{
    __shared__ unsigned WnP[32][64];
    __shared__ unsigned WeP[32][64];
    __shared__ __align__(16) float xs[WPB][192];
    __shared__ __align__(16) float xa[WPB][192];

    for (int t = threadIdx.x; t < 2048; t += 512) {
        int i2 = t >> 6, o = t & 63;
        WnP[i2][o] = f2bf(Wn[o * 64 + 2 * i2]) | (f2bf(Wn[o * 64 + 2 * i2 + 1]) << 16);
        WeP[i2][o] = f2bf(We[o * 64 + 2 * i2]) | (f2bf(We[o * 64 + 2 * i2 + 1]) << 16);
    }
    __syncthreads();

    const int wave = threadIdx.x >> 6;
    const int lane = threadIdx.x & 63;
    const int p = blockIdx.x * WPB + wave;   // 12500*8 = 100000 exact
    const int b = p / N_;
    const int d = p - b * N_;

    const int beg = offsets[d];
    const int end = offsets[d + 1];
    const int deg = end - beg;
    const int* sp = sortedsrc + beg;
    const uint2* xb2 = (const uint2*)xbf + (size_t)b * N_ * 48;

    if (lane < 48) {
        uint2 ov = xb2[(size_t)d * 48 + lane];
        float4 s4;
        s4.x = blo(ov.x); s4.y = bhi(ov.x);
        s4.z = blo(ov.y); s4.w = bhi(ov.y);
        ((float4*)&xs[wave][0])[lane] = s4;

        float ax = 0.f, ay = 0.f, az = 0.f, aw = 0.f;
        int e = 0;
        for (; e + 7 < deg; e += 8) {
            int s0 = sp[e + 0], s1 = sp[e + 1], s2 = sp[e + 2], s3 = sp[e + 3];
            int s4i = sp[e + 4], s5 = sp[e + 5], s6 = sp[e + 6], s7 = sp[e + 7];
            uint2 v0 = xb2[(size_t)s0 * 48 + lane];
            uint2 v1 = xb2[(size_t)s1 * 48 + lane];
            uint2 v2 = xb2[(size_t)s2 * 48 + lane];
            uint2 v3 = xb2[(size_t)s3 * 48 + lane];
            uint2 v4 = xb2[(size_t)s4i * 48 + lane];
            uint2 v5 = xb2[(size_t)s5 * 48 + lane];
            uint2 v6 = xb2[(size_t)s6 * 48 + lane];
            uint2 v7 = xb2[(size_t)s7 * 48 + lane];
            ax += ((blo(v0.x) + blo(v1.x)) + (blo(v2.x) + blo(v3.x)))
                + ((blo(v4.x) + blo(v5.x)) + (blo(v6.x) + blo(v7.x)));
            ay += ((bhi(v0.x) + bhi(v1.x)) + (bhi(v2.x) + bhi(v3.x)))
                + ((bhi(v4.x) + bhi(v5.x)) + (bhi(v6.x) + bhi(v7.x)));
            az += ((blo(v0.y) + blo(v1.y)) + (blo(v2.y) + blo(v3.y)))
                + ((blo(v4.y) + blo(v5.y)) + (blo(v6.y) + blo(v7.y)));
            aw += ((bhi(v0.y) + bhi(v1.y)) + (bhi(v2.y) + bhi(v3.y)))
                + ((bhi(v4.y) + bhi(v5.y)) + (bhi(v6.y) + bhi(v7.y)));
        }
        for (; e < deg; ++e) {
            int s = sp[e];
            uint2 v = xb2[(size_t)s * 48 + lane];
            ax += blo(v.x); ay += bhi(v.x);
            az += blo(v.y); aw += bhi(v.y);
        }
        float4 a4; a4.x = ax; a4.y = ay; a4.z = az; a4.w = aw;
        ((float4*)&xa[wave][0])[lane] = a4;
    }
    // wave-local LDS write->read ordering via lgkmcnt

    float an0 = 0.f, an1 = 0.f, an2 = 0.f;
    float ae0 = 0.f, ae1 = 0.f, ae2 = 0.f;
    const float4* xsv = (const float4*)&xs[wave][0];
    const float4* xav = (const float4*)&xa[wave][0];

    #pragma unroll
    for (int i4 = 0; i4 < 16; ++i4) {
        unsigned un0 = WnP[2 * i4 + 0][lane];
        unsigned un1 = WnP[2 * i4 + 1][lane];
        unsigned ue0 = WeP[2 * i4 + 0][lane];
        unsigned ue1 = WeP[2 * i4 + 1][lane];
        float4 d0 = xsv[i4 * 3 + 0];
        float4 d1 = xsv[i4 * 3 + 1];
        float4 d2 = xsv[i4 * 3 + 2];
        float4 g0 = xav[i4 * 3 + 0];
        float4 g1 = xav[i4 * 3 + 1];
        float4 g2 = xav[i4 * 3 + 2];
        float wn0 = blo(un0), wn1 = bhi(un0), wn2 = blo(un1), wn3 = bhi(un1);
        float we0 = blo(ue0), we1 = bhi(ue0), we2 = blo(ue1), we3 = bhi(ue1);

        an0 = fmaf(wn0, d0.x, an0); an1 = fmaf(wn0, d0.y, an1); an2 = fmaf(wn0, d0.z, an2);
        an0 = fmaf(wn1, d0.w, an0); an1 = fmaf(wn1, d1.x, an1); an2 = fmaf(wn1, d1.y, an2);
        an0 = fmaf(wn2, d1.z, an0); an1 = fmaf(wn2, d1.w, an1); an2 = fmaf(wn2, d2.x, an2);
        an0 = fmaf(wn3, d2.y, an0); an1 = fmaf(wn3, d2.z, an1); an2 = fmaf(wn3, d2.w, an2);

        ae0 = fmaf(we0, g0.x, ae0); ae1 = fmaf(we0, g0.y, ae1); ae2 = fmaf(we0, g0.z, ae2);
        ae0 = fmaf(we1, g0.w, ae0); ae1 = fmaf(we1, g1.x, ae1); ae2 = fmaf(we1, g1.y, ae2);
        ae0 = fmaf(we2, g1.z, ae0); ae1 = fmaf(we2, g1.w, ae1); ae2 = fmaf(we2, g2.x, ae2);
        ae0 = fmaf(we3, g2.y, ae0); ae1 = fmaf(we3, g2.z, ae1); ae2 = fmaf(we3, g2.w, ae2);
    }

    // epilogue: wave-local LDS transpose -> full-line dwordx4 out stores
    const float sc = norm[d];
    float* xw = &xs[wave][0];
    xw[lane * 3 + 0] = INV_SQRT_2 * fmaf(sc, ae0, an0);
    xw[lane * 3 + 1] = INV_SQRT_2 * fmaf(sc, ae1, an1);
    xw[lane * 3 + 2] = INV_SQRT_2 * fmaf(sc, ae2, an2);
    if (lane < 48) {
        float4 o4 = ((const float4*)xw)[lane];
        ((float4*)(out + (size_t)p * 192))[lane] = o4;
    }
}

extern "C" void kernel_launch(void* const* d_in, const int* in_sizes, int n_in,
                              void* d_out, int out_size, void* d_ws, size_t ws_size,
                              hipStream_t stream) {
    const float* x    = (const float*)d_in[0];
    const float* Wn   = (const float*)d_in[1];
    const float* We   = (const float*)d_in[2];
    const float* norm = (const float*)d_in[3];
    const int*   src  = (const int*)d_in[4];
    const int*   dst  = (const int*)d_in[5];
    float* out = (float*)d_out;

    int* ws_i          = (int*)d_ws;
    int* cnt           = ws_i + OFF_CNT;
    int* scanned       = ws_i + OFF_SCAN;
    int* bsum          = ws_i + OFF_BSUM;
    int* bsx           = ws_i + OFF_BSX;
    unsigned* mid      = (unsigned*)(ws_i + OFF_MID);
    int* sortedsrc     = ws_i + OFF_SORT;
    int* offsets       = ws_i + OFF_OFFS;
    unsigned* xbf      = (unsigned*)(ws_i + OFF_XBF);

    hist_conv_kernel<<<HBLK + CONV_BLKS, 256, 0, stream>>>(dst, x, cnt, xbf);
    scan_partial_kernel<<<SBLK, 256, 0, stream>>>(cnt, bsum);
    scan_bsum_kernel<<<1, 256, 0, stream>>>(bsum, bsx);
    scan_final_kernel<<<SBLK, 256, 0, stream>>>(cnt, bsx, scanned);
    mid_scatter_kernel<<<HBLK, 256, 0, stream>>>(src, dst, scanned, mid);
    bucket_sort_kernel<<<HBLK, 256, 0, stream>>>(mid, scanned, sortedsrc, offsets);
    fused_kernel<<<(B_ * N_) / WPB, 512, 0, stream>>>(Wn, We, norm, offsets,
                                                      sortedsrc, xbf, out);
}